// Round 7
// baseline (594.392 us; speedup 1.0000x reference)
//
#include <hip/hip_runtime.h>
#include <hip/hip_bf16.h>

#define U_CNT 339
#define S_CNT 5825
#define N_CNT 6164          // U + S
#define D_DIM 128
#define R_DIM 32
#define B_CNT 500000
#define M_EDGE 400000       // 2*NNZ (symmetrized)
#define H_DIM 64
#define LN_EPS 1e-5f
#define MLP_BLK 128

// fp32 weight-block offsets (elements). W2 stored TRANSPOSED: Wf[WF_W2 + j*64 + k] = W2[k][j]
#define WF_W2   0
#define WF_B1   4096
#define WF_G1   4160
#define WF_BE1  4224
#define WF_B2   4288
#define WF_G2   4352
#define WF_BE2  4416
#define WF_W3   4480
#define WF_B3   4544
#define WF_TOT  4545

typedef __hip_bfloat16 bf16;

__device__ __forceinline__ float b2f(bf16 x) { return __bfloat162float(x); }

// generic float-input load: isf32 selects fp32 vs bf16 interpretation
__device__ __forceinline__ float ldf(const void* p, long i, int isf32) {
    return isf32 ? ((const float*)p)[i] : b2f(((const bf16*)p)[i]);
}

// ---------- init: zero counts + dtype detect (block 0, wave 0) ----------
__global__ void k_init(const void* __restrict__ uE, int* __restrict__ counts,
                       int* __restrict__ flag) {
    int i = blockIdx.x * 256 + threadIdx.x;
    if (i < N_CNT) counts[i] = 0;
    if (blockIdx.x == 0 && threadIdx.x < 64) {
        const unsigned short* p = (const unsigned short*)uE;
        unsigned short v = p[2 * threadIdx.x];       // even bf16 element
        int e = (v >> 7) & 0xFF;                     // bf16 exponent field
        unsigned long long m = __ballot(e >= 127);   // impossible for Xavier bf16
        if (threadIdx.x == 0) flag[0] = (m != 0ull) ? 1 : 0;  // 1 => fp32 buffers
    }
}

// ---------- concat embeddings to fp32 [N,D] + edge histogram (fused) ----------
__global__ void k_pre(const void* __restrict__ uE, const void* __restrict__ iE,
                      float* __restrict__ E, const int* __restrict__ rows,
                      int* __restrict__ counts, const int* __restrict__ flag) {
    int i = blockIdx.x * 256 + threadIdx.x;
    int isf32 = flag[0];
    const int T1 = N_CNT * D_DIM;
    if (i < T1) {
        const int uTot = U_CNT * D_DIM;
        E[i] = (i < uTot) ? ldf(uE, i, isf32) : ldf(iE, i - uTot, isf32);
    }
    if (i < M_EDGE) atomicAdd(&counts[rows[i]], 1);
}

// ---------- CSR build: exclusive scan over N=6164 counts (one 256-thread block) ----------
__global__ void k_scan(const int* __restrict__ counts, int* __restrict__ row_ptr) {
    __shared__ int part[256];
    const int RPT = 25;                               // 256*25 = 6400 >= N+1
    int t = threadIdx.x;
    int base = t * RPT;
    int local[RPT];
    int s = 0;
    #pragma unroll
    for (int i = 0; i < RPT; ++i) {
        int idx = base + i;
        int v = (idx < N_CNT) ? counts[idx] : 0;
        local[i] = s;
        s += v;
    }
    part[t] = s;
    __syncthreads();
    for (int off = 1; off < 256; off <<= 1) {
        int v = (t >= off) ? part[t - off] : 0;
        __syncthreads();
        part[t] += v;
        __syncthreads();
    }
    int prefix = (t > 0) ? part[t - 1] : 0;
    #pragma unroll
    for (int i = 0; i < RPT; ++i) {
        int idx = base + i;
        if (idx <= N_CNT) row_ptr[idx] = prefix + local[i];
    }
}

// ---------- CSR build: scatter, 4 edges/thread, counts[] as down-counter ----------
__global__ void k_scatter(const int* __restrict__ rows, const int* __restrict__ cols,
                          const void* __restrict__ vals, const int* __restrict__ row_ptr,
                          int* __restrict__ counts, int2* __restrict__ csr,
                          const int* __restrict__ flag) {
    int e = (blockIdx.x * 256 + threadIdx.x) * 4;
    if (e >= M_EDGE) return;                          // M_EDGE % 4 == 0
    int isf32 = flag[0];
    int4 r4 = *(const int4*)(rows + e);
    int4 c4 = *(const int4*)(cols + e);
    float v0, v1, v2, v3;
    if (isf32) {
        float4 v = *(const float4*)((const float*)vals + e);
        v0 = v.x; v1 = v.y; v2 = v.z; v3 = v.w;
    } else {
        ushort4 v = *(const ushort4*)((const unsigned short*)vals + e);
        v0 = b2f(*(bf16*)&v.x); v1 = b2f(*(bf16*)&v.y);
        v2 = b2f(*(bf16*)&v.z); v3 = b2f(*(bf16*)&v.w);
    }
    int p0 = atomicSub(&counts[r4.x], 1) - 1;
    int p1 = atomicSub(&counts[r4.y], 1) - 1;
    int p2 = atomicSub(&counts[r4.z], 1) - 1;
    int p3 = atomicSub(&counts[r4.w], 1) - 1;
    csr[row_ptr[r4.x] + p0] = make_int2(c4.x, __float_as_int(v0));
    csr[row_ptr[r4.y] + p1] = make_int2(c4.y, __float_as_int(v1));
    csr[row_ptr[r4.z] + p2] = make_int2(c4.z, __float_as_int(v2));
    csr[row_ptr[r4.w] + p3] = make_int2(c4.w, __float_as_int(v3));
}

// ---------- SpMM: 4 waves per row split the edge list, LDS reduce ----------
__global__ void __launch_bounds__(256)
k_spmm(const float2* __restrict__ Ein2, float2* __restrict__ Eout2,
       const int* __restrict__ row_ptr, const int2* __restrict__ csr) {
    __shared__ float2 part[4][64];
    int r = blockIdx.x;
    int wave = threadIdx.x >> 6;
    int d = threadIdx.x & 63;                         // 2 dims per lane
    int k0 = row_ptr[r], k1 = row_ptr[r + 1];
    int cnt = k1 - k0;
    int chunk = (cnt + 3) >> 2;
    int ck0 = k0 + min(wave * chunk, cnt);
    int ck1 = k0 + min((wave + 1) * chunk, cnt);
    float ax0 = 0, ay0 = 0, ax1 = 0, ay1 = 0, ax2 = 0, ay2 = 0, ax3 = 0, ay3 = 0;
    int k = ck0;
    for (; k + 4 <= ck1; k += 4) {
        int2 e0 = csr[k], e1 = csr[k + 1], e2 = csr[k + 2], e3 = csr[k + 3];
        float2 f0 = Ein2[e0.x * 64 + d], f1 = Ein2[e1.x * 64 + d];
        float2 f2 = Ein2[e2.x * 64 + d], f3 = Ein2[e3.x * 64 + d];
        float v0 = __int_as_float(e0.y), v1 = __int_as_float(e1.y);
        float v2 = __int_as_float(e2.y), v3 = __int_as_float(e3.y);
        ax0 = fmaf(v0, f0.x, ax0); ay0 = fmaf(v0, f0.y, ay0);
        ax1 = fmaf(v1, f1.x, ax1); ay1 = fmaf(v1, f1.y, ay1);
        ax2 = fmaf(v2, f2.x, ax2); ay2 = fmaf(v2, f2.y, ay2);
        ax3 = fmaf(v3, f3.x, ax3); ay3 = fmaf(v3, f3.y, ay3);
    }
    for (; k < ck1; ++k) {
        int2 e = csr[k];
        float v = __int_as_float(e.y);
        float2 f = Ein2[e.x * 64 + d];
        ax0 = fmaf(v, f.x, ax0); ay0 = fmaf(v, f.y, ay0);
    }
    float2 o;
    o.x = (ax0 + ax1) + (ax2 + ax3);
    o.y = (ay0 + ay1) + (ay2 + ay3);
    part[wave][d] = o;
    __syncthreads();
    if (wave == 0) {
        float2 a = part[0][d], b = part[1][d], c = part[2][d], e = part[3][d];
        float2 s;
        s.x = (a.x + b.x) + (c.x + e.x);
        s.y = (a.y + b.y) + (c.y + e.y);
        Eout2[r * 64 + d] = s;
    }
}

// ---------- blocks 0,1: P = Hyperᵀ(Hyper @ W1part); block 2: weights→fp32 (W2 transposed) ----------
__global__ void k_hyperP(const void* __restrict__ uHy, const void* __restrict__ iHy,
                         const void* __restrict__ W1, const void* __restrict__ W2,
                         const void* __restrict__ b1, const void* __restrict__ g1,
                         const void* __restrict__ be1, const void* __restrict__ b2,
                         const void* __restrict__ g2, const void* __restrict__ be2,
                         const void* __restrict__ W3, const void* __restrict__ b3,
                         float* __restrict__ P, float* __restrict__ Wf,
                         const int* __restrict__ flag) {
    int isf32 = flag[0];
    if (blockIdx.x == 2) {                            // weight prep
        for (int i = threadIdx.x; i < 4096; i += 256) {
            int j = i >> 6, k = i & 63;               // Wf W2 block = W2^T
            Wf[WF_W2 + j * 64 + k] = ldf(W2, k * 64 + j, isf32);
        }
        for (int i = threadIdx.x; i < WF_TOT - 4096; i += 256) {
            int g = 4096 + i;
            float v;
            if      (g < WF_G1)  v = ldf(b1,  g - WF_B1,   isf32);
            else if (g < WF_BE1) v = ldf(g1,  g - WF_G1,   isf32);
            else if (g < WF_B2)  v = ldf(be1, g - WF_BE1,  isf32);
            else if (g < WF_G2)  v = ldf(b2,  g - WF_B2,   isf32);
            else if (g < WF_BE2) v = ldf(g2,  g - WF_G2,   isf32);
            else if (g < WF_W3)  v = ldf(be2, g - WF_BE2,  isf32);
            else if (g < WF_B3)  v = ldf(W3,  g - WF_W3,   isf32);
            else                 v = ldf(b3,  0,           isf32);
            Wf[g] = v;
        }
        return;
    }
    int side = blockIdx.x;                            // 0 = user, 1 = service
    const void* Hy = side ? iHy : uHy;                // [32][128]
    long wbase = (long)side * D_DIM * H_DIM;          // rows [side*128 .. +128) of W1
    __shared__ float Hs[R_DIM * D_DIM];               // 16 KB
    __shared__ float T[R_DIM * H_DIM];                // 8 KB
    for (int idx = threadIdx.x; idx < R_DIM * D_DIM; idx += 256)
        Hs[idx] = ldf(Hy, idx, isf32);
    __syncthreads();
    for (int idx = threadIdx.x; idx < R_DIM * H_DIM; idx += 256) {
        int a = idx >> 6, j = idx & 63;
        float acc = 0.f;
        for (int d = 0; d < D_DIM; ++d)
            acc = fmaf(Hs[a * D_DIM + d], ldf(W1, wbase + d * H_DIM + j, isf32), acc);
        T[idx] = acc;
    }
    __syncthreads();
    for (int idx = threadIdx.x; idx < D_DIM * H_DIM; idx += 256) {
        int d = idx >> 6, j = idx & 63;
        float acc = 0.f;
        #pragma unroll
        for (int a = 0; a < R_DIM; ++a)
            acc = fmaf(Hs[a * D_DIM + d], T[a * H_DIM + j], acc);
        P[side * D_DIM * H_DIM + idx] = acc;
    }
}

// ---------- A[r,:] = E[r,:] @ P(side) (+ b1 folded into user rows) ----------
__global__ void k_A(const float* __restrict__ E, const float* __restrict__ P,
                    const float* __restrict__ Wf, float* __restrict__ A) {
    int r = blockIdx.x;
    int j = threadIdx.x;                              // 64 threads
    const float* Pr = P + ((r < U_CNT) ? 0 : D_DIM * H_DIM);
    const float* Er = E + r * D_DIM;                  // wave-uniform -> scalar loads
    float acc = (r < U_CNT) ? Wf[WF_B1 + j] : 0.f;
    #pragma unroll 8
    for (int d = 0; d < D_DIM; ++d)
        acc = fmaf(Er[d], Pr[d * H_DIM + j], acc);
    A[r * H_DIM + j] = acc;
}

// ---------- fused MLP: one row/thread; y spilled to PRIVATE LDS slice ----------
// R5/R6 post-mortems: the register allocator refuses to keep y[64] resident
// (76-88 VGPR) and RECOMPUTES the 4096-FMA W2 matmul for the post-LN2 pass
// (VALU busy = 2x floor). Fix structurally: compute each y_j once (h in
// registers, W2^T wave-uniform via s_load), accumulate LN2 stats inline,
// store y_j to a per-thread LDS slice (stride 65 floats -> 2-way bank
// aliasing, free per m136), re-read for the G2/ReLU/W3 pass. No syncthreads:
// slices are thread-private.
__global__ void __launch_bounds__(MLP_BLK)
HyperModel_65755949301857_kernel(
      const float* __restrict__ A, const int* __restrict__ userIdx,
      const int* __restrict__ servIdx, const float* __restrict__ Wf,
      void* __restrict__ out, const int* __restrict__ flag) {
    __shared__ float ybuf[MLP_BLK * 65];              // 33,280 B
    int b = blockIdx.x * MLP_BLK + threadIdx.x;
    if (b >= B_CNT) return;
    int isf32 = flag[0];
    int ui = userIdx[b];
    int si = servIdx[b] + U_CNT;
    const float4* A4 = (const float4*)A;
    float* my = ybuf + threadIdx.x * 65;

    // z = A_u[ui] + A_s[si]  (b1 pre-folded into A_u) -- gathered ONCE
    float4 za[16];
    #pragma unroll
    for (int q = 0; q < 16; ++q) {
        float4 a = A4[ui * 16 + q];
        float4 s = A4[si * 16 + q];
        za[q].x = a.x + s.x;
        za[q].y = a.y + s.y;
        za[q].z = a.z + s.z;
        za[q].w = a.w + s.w;
    }
    // LayerNorm 1 (in-register tree sums)
    float s0 = 0, s1 = 0, s2 = 0, s3 = 0, q0 = 0, q1 = 0, q2 = 0, q3 = 0;
    #pragma unroll
    for (int q = 0; q < 16; ++q) {
        s0 += za[q].x; q0 = fmaf(za[q].x, za[q].x, q0);
        s1 += za[q].y; q1 = fmaf(za[q].y, za[q].y, q1);
        s2 += za[q].z; q2 = fmaf(za[q].z, za[q].z, q2);
        s3 += za[q].w; q3 = fmaf(za[q].w, za[q].w, q3);
    }
    float mu  = ((s0 + s1) + (s2 + s3)) * (1.f / 64.f);
    float ex2 = ((q0 + q1) + (q2 + q3)) * (1.f / 64.f);
    float rs = rsqrtf(ex2 - mu * mu + LN_EPS);
    float nmrs = -mu * rs;
    #pragma unroll
    for (int q = 0; q < 16; ++q) {
        za[q].x = fmaxf(fmaf(fmaf(za[q].x, rs, nmrs), Wf[WF_G1 + 4 * q + 0], Wf[WF_BE1 + 4 * q + 0]), 0.f);
        za[q].y = fmaxf(fmaf(fmaf(za[q].y, rs, nmrs), Wf[WF_G1 + 4 * q + 1], Wf[WF_BE1 + 4 * q + 1]), 0.f);
        za[q].z = fmaxf(fmaf(fmaf(za[q].z, rs, nmrs), Wf[WF_G1 + 4 * q + 2], Wf[WF_BE1 + 4 * q + 2]), 0.f);
        za[q].w = fmaxf(fmaf(fmaf(za[q].w, rs, nmrs), Wf[WF_G1 + 4 * q + 3], Wf[WF_BE1 + 4 * q + 3]), 0.f);
    }
    // y_j = h . W2T[j] + b2_j, computed ONCE; LN2 stats inline; y -> LDS
    float ss = 0, qq = 0;
    #pragma unroll 8
    for (int j = 0; j < 64; ++j) {
        const float* wc = Wf + WF_W2 + j * 64;        // wave-uniform -> s_load
        float a0 = 0, a1 = 0, a2 = 0, a3 = 0;
        #pragma unroll
        for (int k = 0; k < 16; ++k) {
            a0 = fmaf(za[k].x, wc[4 * k + 0], a0);
            a1 = fmaf(za[k].y, wc[4 * k + 1], a1);
            a2 = fmaf(za[k].z, wc[4 * k + 2], a2);
            a3 = fmaf(za[k].w, wc[4 * k + 3], a3);
        }
        float yj = ((a0 + a1) + (a2 + a3)) + Wf[WF_B2 + j];
        ss += yj;
        qq = fmaf(yj, yj, qq);
        my[j] = yj;
    }
    mu  = ss * (1.f / 64.f);
    ex2 = qq * (1.f / 64.f);
    float rs2 = rsqrtf(ex2 - mu * mu + LN_EPS);
    float nmrs2 = -mu * rs2;
    float o0 = 0, o1 = 0, o2 = 0, o3 = 0;
    #pragma unroll 8
    for (int j = 0; j < 64; j += 4) {
        float y0 = my[j], y1 = my[j + 1], y2 = my[j + 2], y3 = my[j + 3];
        float t0 = fmaxf(fmaf(fmaf(y0, rs2, nmrs2), Wf[WF_G2 + j],     Wf[WF_BE2 + j]),     0.f);
        float t1 = fmaxf(fmaf(fmaf(y1, rs2, nmrs2), Wf[WF_G2 + j + 1], Wf[WF_BE2 + j + 1]), 0.f);
        float t2 = fmaxf(fmaf(fmaf(y2, rs2, nmrs2), Wf[WF_G2 + j + 2], Wf[WF_BE2 + j + 2]), 0.f);
        float t3 = fmaxf(fmaf(fmaf(y3, rs2, nmrs2), Wf[WF_G2 + j + 3], Wf[WF_BE2 + j + 3]), 0.f);
        o0 = fmaf(t0, Wf[WF_W3 + j],     o0);
        o1 = fmaf(t1, Wf[WF_W3 + j + 1], o1);
        o2 = fmaf(t2, Wf[WF_W3 + j + 2], o2);
        o3 = fmaf(t3, Wf[WF_W3 + j + 3], o3);
    }
    float o = ((o0 + o1) + (o2 + o3)) + Wf[WF_B3];
    if (isf32) ((float*)out)[b] = o;
    else       ((bf16*)out)[b] = __float2bfloat16(o);
}

extern "C" __attribute__((visibility("default")))
void kernel_launch(void* const* d_in, const int* in_sizes, int n_in,
                   void* d_out, int out_size, void* d_ws, size_t ws_size,
                   hipStream_t stream) {
    const void* uE   = d_in[0];
    const void* iE   = d_in[1];
    const void* uHy  = d_in[2];
    const void* iHy  = d_in[3];
    const void* W1   = d_in[4];
    const void* b1   = d_in[5];
    const void* g1   = d_in[6];
    const void* be1  = d_in[7];
    const void* W2   = d_in[8];
    const void* b2   = d_in[9];
    const void* g2   = d_in[10];
    const void* be2  = d_in[11];
    const void* W3   = d_in[12];
    const void* b3   = d_in[13];
    const void* adj_vals = d_in[14];
    const int*  adj_rows = (const int*)d_in[15];
    const int*  adj_cols = (const int*)d_in[16];
    const int*  userIdx  = (const int*)d_in[17];
    const int*  servIdx  = (const int*)d_in[18];

    char* w = (char*)d_ws;
    size_t off = 0;
    auto alloc = [&](size_t bytes) -> char* {
        char* p = w + off;
        off += (bytes + 255) & ~(size_t)255;
        return p;
    };
    float* E0      = (float*)alloc((size_t)N_CNT * D_DIM * 4);
    float* E1      = (float*)alloc((size_t)N_CNT * D_DIM * 4);
    float* P       = (float*)alloc((size_t)2 * D_DIM * H_DIM * 4);
    float* A       = (float*)alloc((size_t)N_CNT * H_DIM * 4);
    int2*  csr     = (int2*)alloc((size_t)M_EDGE * 8);
    int*   row_ptr = (int*)alloc((size_t)(N_CNT + 1) * 4);
    int*   counts  = (int*)alloc((size_t)N_CNT * 4);
    int*   flag    = (int*)alloc(256);
    float* Wf      = (float*)alloc((size_t)WF_TOT * 4);

    k_init<<<(N_CNT + 255) / 256, 256, 0, stream>>>(uE, counts, flag);
    k_pre<<<(N_CNT * D_DIM + 255) / 256, 256, 0, stream>>>(uE, iE, E0, adj_rows, counts, flag);
    k_scan<<<1, 256, 0, stream>>>(counts, row_ptr);
    k_scatter<<<(M_EDGE / 4 + 255) / 256, 256, 0, stream>>>(adj_rows, adj_cols, adj_vals,
                                                            row_ptr, counts, csr, flag);
    // 3 propagation hops: E0 -> E1 -> E0 -> E1
    k_spmm<<<N_CNT, 256, 0, stream>>>((const float2*)E0, (float2*)E1, row_ptr, csr);
    k_spmm<<<N_CNT, 256, 0, stream>>>((const float2*)E1, (float2*)E0, row_ptr, csr);
    k_spmm<<<N_CNT, 256, 0, stream>>>((const float2*)E0, (float2*)E1, row_ptr, csr);

    k_hyperP<<<3, 256, 0, stream>>>(uHy, iHy, W1, W2, b1, g1, be1, b2, g2, be2, W3, b3,
                                    P, Wf, flag);
    k_A<<<N_CNT, H_DIM, 0, stream>>>(E1, P, Wf, A);

    HyperModel_65755949301857_kernel<<<(B_CNT + MLP_BLK - 1) / MLP_BLK, MLP_BLK, 0, stream>>>(
        A, userIdx, servIdx, Wf, d_out, flag);
}

// Round 8
// 581.839 us; speedup vs baseline: 1.0216x; 1.0216x over previous
//
#include <hip/hip_runtime.h>
#include <hip/hip_bf16.h>

#define U_CNT 339
#define S_CNT 5825
#define N_CNT 6164          // U + S
#define D_DIM 128
#define R_DIM 32
#define B_CNT 500000
#define M_EDGE 400000       // 2*NNZ (symmetrized)
#define H_DIM 64
#define LN_EPS 1e-5f

// fp32 weight-block offsets (elements). W2 stored TRANSPOSED: Wf[WF_W2 + j*64 + k] = W2[k][j]
#define WF_W2   0
#define WF_B1   4096
#define WF_G1   4160
#define WF_BE1  4224
#define WF_B2   4288
#define WF_G2   4352
#define WF_BE2  4416
#define WF_W3   4480
#define WF_B3   4544
#define WF_TOT  4545

#define HPAD 66             // LDS row stride (floats): 2-way bank aliasing max (free)

typedef __hip_bfloat16 bf16;

__device__ __forceinline__ float b2f(bf16 x) { return __bfloat162float(x); }

// generic float-input load: isf32 selects fp32 vs bf16 interpretation
__device__ __forceinline__ float ldf(const void* p, long i, int isf32) {
    return isf32 ? ((const float*)p)[i] : b2f(((const bf16*)p)[i]);
}

// ---------- init: zero counts + dtype detect (block 0, wave 0) ----------
__global__ void k_init(const void* __restrict__ uE, int* __restrict__ counts,
                       int* __restrict__ flag) {
    int i = blockIdx.x * 256 + threadIdx.x;
    if (i < N_CNT) counts[i] = 0;
    if (blockIdx.x == 0 && threadIdx.x < 64) {
        const unsigned short* p = (const unsigned short*)uE;
        unsigned short v = p[2 * threadIdx.x];       // even bf16 element
        int e = (v >> 7) & 0xFF;                     // bf16 exponent field
        unsigned long long m = __ballot(e >= 127);   // impossible for Xavier bf16
        if (threadIdx.x == 0) flag[0] = (m != 0ull) ? 1 : 0;  // 1 => fp32 buffers
    }
}

// ---------- concat embeddings to fp32 [N,D] + edge histogram (fused) ----------
__global__ void k_pre(const void* __restrict__ uE, const void* __restrict__ iE,
                      float* __restrict__ E, const int* __restrict__ rows,
                      int* __restrict__ counts, const int* __restrict__ flag) {
    int i = blockIdx.x * 256 + threadIdx.x;
    int isf32 = flag[0];
    const int T1 = N_CNT * D_DIM;
    if (i < T1) {
        const int uTot = U_CNT * D_DIM;
        E[i] = (i < uTot) ? ldf(uE, i, isf32) : ldf(iE, i - uTot, isf32);
    }
    if (i < M_EDGE) atomicAdd(&counts[rows[i]], 1);
}

// ---------- CSR build: exclusive scan over N=6164 counts (one 256-thread block) ----------
__global__ void k_scan(const int* __restrict__ counts, int* __restrict__ row_ptr) {
    __shared__ int part[256];
    const int RPT = 25;                               // 256*25 = 6400 >= N+1
    int t = threadIdx.x;
    int base = t * RPT;
    int local[RPT];
    int s = 0;
    #pragma unroll
    for (int i = 0; i < RPT; ++i) {
        int idx = base + i;
        int v = (idx < N_CNT) ? counts[idx] : 0;
        local[i] = s;
        s += v;
    }
    part[t] = s;
    __syncthreads();
    for (int off = 1; off < 256; off <<= 1) {
        int v = (t >= off) ? part[t - off] : 0;
        __syncthreads();
        part[t] += v;
        __syncthreads();
    }
    int prefix = (t > 0) ? part[t - 1] : 0;
    #pragma unroll
    for (int i = 0; i < RPT; ++i) {
        int idx = base + i;
        if (idx <= N_CNT) row_ptr[idx] = prefix + local[i];
    }
}

// ---------- CSR build: scatter, 4 edges/thread, counts[] as down-counter ----------
__global__ void k_scatter(const int* __restrict__ rows, const int* __restrict__ cols,
                          const void* __restrict__ vals, const int* __restrict__ row_ptr,
                          int* __restrict__ counts, int2* __restrict__ csr,
                          const int* __restrict__ flag) {
    int e = (blockIdx.x * 256 + threadIdx.x) * 4;
    if (e >= M_EDGE) return;                          // M_EDGE % 4 == 0
    int isf32 = flag[0];
    int4 r4 = *(const int4*)(rows + e);
    int4 c4 = *(const int4*)(cols + e);
    float v0, v1, v2, v3;
    if (isf32) {
        float4 v = *(const float4*)((const float*)vals + e);
        v0 = v.x; v1 = v.y; v2 = v.z; v3 = v.w;
    } else {
        ushort4 v = *(const ushort4*)((const unsigned short*)vals + e);
        v0 = b2f(*(bf16*)&v.x); v1 = b2f(*(bf16*)&v.y);
        v2 = b2f(*(bf16*)&v.z); v3 = b2f(*(bf16*)&v.w);
    }
    int p0 = atomicSub(&counts[r4.x], 1) - 1;
    int p1 = atomicSub(&counts[r4.y], 1) - 1;
    int p2 = atomicSub(&counts[r4.z], 1) - 1;
    int p3 = atomicSub(&counts[r4.w], 1) - 1;
    csr[row_ptr[r4.x] + p0] = make_int2(c4.x, __float_as_int(v0));
    csr[row_ptr[r4.y] + p1] = make_int2(c4.y, __float_as_int(v1));
    csr[row_ptr[r4.z] + p2] = make_int2(c4.z, __float_as_int(v2));
    csr[row_ptr[r4.w] + p3] = make_int2(c4.w, __float_as_int(v3));
}

// ---------- SpMM: 4 waves per row split the edge list, LDS reduce ----------
__global__ void __launch_bounds__(256)
k_spmm(const float2* __restrict__ Ein2, float2* __restrict__ Eout2,
       const int* __restrict__ row_ptr, const int2* __restrict__ csr) {
    __shared__ float2 part[4][64];
    int r = blockIdx.x;
    int wave = threadIdx.x >> 6;
    int d = threadIdx.x & 63;                         // 2 dims per lane
    int k0 = row_ptr[r], k1 = row_ptr[r + 1];
    int cnt = k1 - k0;
    int chunk = (cnt + 3) >> 2;
    int ck0 = k0 + min(wave * chunk, cnt);
    int ck1 = k0 + min((wave + 1) * chunk, cnt);
    float ax0 = 0, ay0 = 0, ax1 = 0, ay1 = 0, ax2 = 0, ay2 = 0, ax3 = 0, ay3 = 0;
    int k = ck0;
    for (; k + 4 <= ck1; k += 4) {
        int2 e0 = csr[k], e1 = csr[k + 1], e2 = csr[k + 2], e3 = csr[k + 3];
        float2 f0 = Ein2[e0.x * 64 + d], f1 = Ein2[e1.x * 64 + d];
        float2 f2 = Ein2[e2.x * 64 + d], f3 = Ein2[e3.x * 64 + d];
        float v0 = __int_as_float(e0.y), v1 = __int_as_float(e1.y);
        float v2 = __int_as_float(e2.y), v3 = __int_as_float(e3.y);
        ax0 = fmaf(v0, f0.x, ax0); ay0 = fmaf(v0, f0.y, ay0);
        ax1 = fmaf(v1, f1.x, ax1); ay1 = fmaf(v1, f1.y, ay1);
        ax2 = fmaf(v2, f2.x, ax2); ay2 = fmaf(v2, f2.y, ay2);
        ax3 = fmaf(v3, f3.x, ax3); ay3 = fmaf(v3, f3.y, ay3);
    }
    for (; k < ck1; ++k) {
        int2 e = csr[k];
        float v = __int_as_float(e.y);
        float2 f = Ein2[e.x * 64 + d];
        ax0 = fmaf(v, f.x, ax0); ay0 = fmaf(v, f.y, ay0);
    }
    float2 o;
    o.x = (ax0 + ax1) + (ax2 + ax3);
    o.y = (ay0 + ay1) + (ay2 + ay3);
    part[wave][d] = o;
    __syncthreads();
    if (wave == 0) {
        float2 a = part[0][d], b = part[1][d], c = part[2][d], e = part[3][d];
        float2 s;
        s.x = (a.x + b.x) + (c.x + e.x);
        s.y = (a.y + b.y) + (c.y + e.y);
        Eout2[r * 64 + d] = s;
    }
}

// ---------- blocks 0,1: P = Hyperᵀ(Hyper @ W1part); block 2: weights→fp32 (W2 transposed) ----------
__global__ void k_hyperP(const void* __restrict__ uHy, const void* __restrict__ iHy,
                         const void* __restrict__ W1, const void* __restrict__ W2,
                         const void* __restrict__ b1, const void* __restrict__ g1,
                         const void* __restrict__ be1, const void* __restrict__ b2,
                         const void* __restrict__ g2, const void* __restrict__ be2,
                         const void* __restrict__ W3, const void* __restrict__ b3,
                         float* __restrict__ P, float* __restrict__ Wf,
                         const int* __restrict__ flag) {
    int isf32 = flag[0];
    if (blockIdx.x == 2) {                            // weight prep
        for (int i = threadIdx.x; i < 4096; i += 256) {
            int j = i >> 6, k = i & 63;               // Wf W2 block = W2^T
            Wf[WF_W2 + j * 64 + k] = ldf(W2, k * 64 + j, isf32);
        }
        for (int i = threadIdx.x; i < WF_TOT - 4096; i += 256) {
            int g = 4096 + i;
            float v;
            if      (g < WF_G1)  v = ldf(b1,  g - WF_B1,   isf32);
            else if (g < WF_BE1) v = ldf(g1,  g - WF_G1,   isf32);
            else if (g < WF_B2)  v = ldf(be1, g - WF_BE1,  isf32);
            else if (g < WF_G2)  v = ldf(b2,  g - WF_B2,   isf32);
            else if (g < WF_BE2) v = ldf(g2,  g - WF_G2,   isf32);
            else if (g < WF_W3)  v = ldf(be2, g - WF_BE2,  isf32);
            else if (g < WF_B3)  v = ldf(W3,  g - WF_W3,   isf32);
            else                 v = ldf(b3,  0,           isf32);
            Wf[g] = v;
        }
        return;
    }
    int side = blockIdx.x;                            // 0 = user, 1 = service
    const void* Hy = side ? iHy : uHy;                // [32][128]
    long wbase = (long)side * D_DIM * H_DIM;          // rows [side*128 .. +128) of W1
    __shared__ float Hs[R_DIM * D_DIM];               // 16 KB
    __shared__ float T[R_DIM * H_DIM];                // 8 KB
    for (int idx = threadIdx.x; idx < R_DIM * D_DIM; idx += 256)
        Hs[idx] = ldf(Hy, idx, isf32);
    __syncthreads();
    for (int idx = threadIdx.x; idx < R_DIM * H_DIM; idx += 256) {
        int a = idx >> 6, j = idx & 63;
        float acc = 0.f;
        for (int d = 0; d < D_DIM; ++d)
            acc = fmaf(Hs[a * D_DIM + d], ldf(W1, wbase + d * H_DIM + j, isf32), acc);
        T[idx] = acc;
    }
    __syncthreads();
    for (int idx = threadIdx.x; idx < D_DIM * H_DIM; idx += 256) {
        int d = idx >> 6, j = idx & 63;
        float acc = 0.f;
        #pragma unroll
        for (int a = 0; a < R_DIM; ++a)
            acc = fmaf(Hs[a * D_DIM + d], T[a * H_DIM + j], acc);
        P[side * D_DIM * H_DIM + idx] = acc;
    }
}

// ---------- A[r,:] = E[r,:] @ P(side) (+ b1 folded into user rows) ----------
__global__ void k_A(const float* __restrict__ E, const float* __restrict__ P,
                    const float* __restrict__ Wf, float* __restrict__ A) {
    int r = blockIdx.x;
    int j = threadIdx.x;                              // 64 threads
    const float* Pr = P + ((r < U_CNT) ? 0 : D_DIM * H_DIM);
    const float* Er = E + r * D_DIM;                  // wave-uniform -> scalar loads
    float acc = (r < U_CNT) ? Wf[WF_B1 + j] : 0.f;
    #pragma unroll 8
    for (int d = 0; d < D_DIM; ++d)
        acc = fmaf(Er[d], Pr[d * H_DIM + j], acc);
    A[r * H_DIM + j] = acc;
}

// ---------- fused MLP: block-tiled GEMM, 128 rows x 64 cols per block ----------
// R5-R7 lesson: per-thread 64-float arrays lose (allocator caps ~88 VGPR,
// recomputes or serializes). This design's per-thread state is y[8][4]=32
// regs -- fits the default budget. Phase 1: 2 thr/row gather+LN1+ReLU -> h in
// LDS (stride 66: <=2-way bank aliasing, free). Phase 2: thread (rg,cg) does
// 8 rows x 4 cols; h via wave-broadcast ds_read_b64, W2^T via L1 float2.
// Phase 3/4: LN2 + epilogue via shfl_xor butterflies over the 16 cg lanes.
__global__ void __launch_bounds__(256)
HyperModel_65755949301857_kernel(
      const float* __restrict__ A, const int* __restrict__ userIdx,
      const int* __restrict__ servIdx, const float* __restrict__ Wf,
      void* __restrict__ out, const int* __restrict__ flag) {
    __shared__ float h[128 * HPAD];                   // 33,792 B
    int tid = threadIdx.x;
    int b0 = blockIdx.x * 128;
    int isf32 = flag[0];

    // ---- Phase 1: gather + LN1 + ReLU -> h LDS (2 threads per row) ----
    {
        int row = tid >> 1, half = tid & 1;
        int b = b0 + row;
        float4 zz[8];
        if (b < B_CNT) {
            int ui = userIdx[b];
            int si = servIdx[b] + U_CNT;
            const float4* Au = (const float4*)A + ui * 16 + half * 8;
            const float4* As = (const float4*)A + si * 16 + half * 8;
            #pragma unroll
            for (int q = 0; q < 8; ++q) {
                float4 a = Au[q], s = As[q];
                zz[q].x = a.x + s.x; zz[q].y = a.y + s.y;
                zz[q].z = a.z + s.z; zz[q].w = a.w + s.w;
            }
        } else {
            #pragma unroll
            for (int q = 0; q < 8; ++q) zz[q] = make_float4(0.f, 0.f, 0.f, 0.f);
        }
        float s0 = 0, s1 = 0, q0 = 0, q1 = 0;
        #pragma unroll
        for (int q = 0; q < 8; ++q) {
            s0 += zz[q].x + zz[q].z;
            s1 += zz[q].y + zz[q].w;
            q0 = fmaf(zz[q].x, zz[q].x, q0); q0 = fmaf(zz[q].z, zz[q].z, q0);
            q1 = fmaf(zz[q].y, zz[q].y, q1); q1 = fmaf(zz[q].w, zz[q].w, q1);
        }
        float ss = s0 + s1, qq = q0 + q1;
        ss += __shfl_xor(ss, 1, 64);                  // combine with partner half
        qq += __shfl_xor(qq, 1, 64);
        float mu  = ss * (1.f / 64.f);
        float ex2 = qq * (1.f / 64.f);
        float rs = rsqrtf(ex2 - mu * mu + LN_EPS);
        float nmrs = -mu * rs;
        const float4* G1 = (const float4*)(Wf + WF_G1) + half * 8;
        const float4* BE1 = (const float4*)(Wf + WF_BE1) + half * 8;
        float* hr = h + row * HPAD + half * 32;
        #pragma unroll
        for (int q = 0; q < 8; ++q) {
            float4 g = G1[q], be = BE1[q];
            float2 a, c;
            a.x = fmaxf(fmaf(fmaf(zz[q].x, rs, nmrs), g.x, be.x), 0.f);
            a.y = fmaxf(fmaf(fmaf(zz[q].y, rs, nmrs), g.y, be.y), 0.f);
            c.x = fmaxf(fmaf(fmaf(zz[q].z, rs, nmrs), g.z, be.z), 0.f);
            c.y = fmaxf(fmaf(fmaf(zz[q].w, rs, nmrs), g.w, be.w), 0.f);
            *(float2*)(hr + 4 * q) = a;               // 8B-aligned (266*row etc.)
            *(float2*)(hr + 4 * q + 2) = c;
        }
    }
    __syncthreads();

    // ---- Phase 2: y[8][4] = h(8 rows) @ W2T(4 cols) ----
    int cg = tid & 15;                                // cols cg*4 .. +3
    int rg = tid >> 4;                                // rows rg*8 .. +7
    const float2* W2T2 = (const float2*)(Wf + WF_W2);
    float y[8][4];
    {
        const float* B2p = Wf + WF_B2 + cg * 4;
        float bb0 = B2p[0], bb1 = B2p[1], bb2 = B2p[2], bb3 = B2p[3];
        #pragma unroll
        for (int i = 0; i < 8; ++i) {
            y[i][0] = bb0; y[i][1] = bb1; y[i][2] = bb2; y[i][3] = bb3;
        }
    }
    const float* hbase = h + rg * 8 * HPAD;
    #pragma unroll 4
    for (int k = 0; k < 64; k += 2) {
        float2 w0 = W2T2[(cg * 4 + 0) * 32 + (k >> 1)];
        float2 w1 = W2T2[(cg * 4 + 1) * 32 + (k >> 1)];
        float2 w2 = W2T2[(cg * 4 + 2) * 32 + (k >> 1)];
        float2 w3 = W2T2[(cg * 4 + 3) * 32 + (k >> 1)];
        #pragma unroll
        for (int i = 0; i < 8; ++i) {
            float2 hh = *(const float2*)(hbase + i * HPAD + k);
            y[i][0] = fmaf(hh.x, w0.x, fmaf(hh.y, w0.y, y[i][0]));
            y[i][1] = fmaf(hh.x, w1.x, fmaf(hh.y, w1.y, y[i][1]));
            y[i][2] = fmaf(hh.x, w2.x, fmaf(hh.y, w2.y, y[i][2]));
            y[i][3] = fmaf(hh.x, w3.x, fmaf(hh.y, w3.y, y[i][3]));
        }
    }

    // ---- Phase 3: LN2 stats per row via butterfly over 16 cg lanes ----
    float s[8], q[8];
    #pragma unroll
    for (int i = 0; i < 8; ++i) {
        s[i] = (y[i][0] + y[i][1]) + (y[i][2] + y[i][3]);
        float qa = fmaf(y[i][0], y[i][0], 0.f);
        qa = fmaf(y[i][1], y[i][1], qa);
        qa = fmaf(y[i][2], y[i][2], qa);
        qa = fmaf(y[i][3], y[i][3], qa);
        q[i] = qa;
    }
    #pragma unroll
    for (int off = 1; off < 16; off <<= 1) {
        #pragma unroll
        for (int i = 0; i < 8; ++i) {
            s[i] += __shfl_xor(s[i], off, 64);
            q[i] += __shfl_xor(q[i], off, 64);
        }
    }
    // ---- Phase 4: scale+ReLU+W3 partial, butterfly-reduce, store ----
    const float* G2p = Wf + WF_G2 + cg * 4;
    const float* BE2p = Wf + WF_BE2 + cg * 4;
    const float* W3p = Wf + WF_W3 + cg * 4;
    float g20 = G2p[0], g21 = G2p[1], g22 = G2p[2], g23 = G2p[3];
    float be20 = BE2p[0], be21 = BE2p[1], be22 = BE2p[2], be23 = BE2p[3];
    float w30 = W3p[0], w31 = W3p[1], w32 = W3p[2], w33 = W3p[3];
    float b3v = Wf[WF_B3];
    float o[8];
    #pragma unroll
    for (int i = 0; i < 8; ++i) {
        float mu  = s[i] * (1.f / 64.f);
        float ex2 = q[i] * (1.f / 64.f);
        float rs2 = rsqrtf(ex2 - mu * mu + LN_EPS);
        float nm = -mu * rs2;
        float t0 = fmaxf(fmaf(fmaf(y[i][0], rs2, nm), g20, be20), 0.f);
        float t1 = fmaxf(fmaf(fmaf(y[i][1], rs2, nm), g21, be21), 0.f);
        float t2 = fmaxf(fmaf(fmaf(y[i][2], rs2, nm), g22, be22), 0.f);
        float t3 = fmaxf(fmaf(fmaf(y[i][3], rs2, nm), g23, be23), 0.f);
        o[i] = fmaf(t0, w30, fmaf(t1, w31, fmaf(t2, w32, t3 * w33)));
    }
    #pragma unroll
    for (int off = 1; off < 16; off <<= 1) {
        #pragma unroll
        for (int i = 0; i < 8; ++i) o[i] += __shfl_xor(o[i], off, 64);
    }
    if (cg == 0) {
        #pragma unroll
        for (int i = 0; i < 8; ++i) {
            int b = b0 + rg * 8 + i;
            if (b < B_CNT) {
                float r = o[i] + b3v;
                if (isf32) ((float*)out)[b] = r;
                else       ((bf16*)out)[b] = __float2bfloat16(r);
            }
        }
    }
}

extern "C" __attribute__((visibility("default")))
void kernel_launch(void* const* d_in, const int* in_sizes, int n_in,
                   void* d_out, int out_size, void* d_ws, size_t ws_size,
                   hipStream_t stream) {
    const void* uE   = d_in[0];
    const void* iE   = d_in[1];
    const void* uHy  = d_in[2];
    const void* iHy  = d_in[3];
    const void* W1   = d_in[4];
    const void* b1   = d_in[5];
    const void* g1   = d_in[6];
    const void* be1  = d_in[7];
    const void* W2   = d_in[8];
    const void* b2   = d_in[9];
    const void* g2   = d_in[10];
    const void* be2  = d_in[11];
    const void* W3   = d_in[12];
    const void* b3   = d_in[13];
    const void* adj_vals = d_in[14];
    const int*  adj_rows = (const int*)d_in[15];
    const int*  adj_cols = (const int*)d_in[16];
    const int*  userIdx  = (const int*)d_in[17];
    const int*  servIdx  = (const int*)d_in[18];

    char* w = (char*)d_ws;
    size_t off = 0;
    auto alloc = [&](size_t bytes) -> char* {
        char* p = w + off;
        off += (bytes + 255) & ~(size_t)255;
        return p;
    };
    float* E0      = (float*)alloc((size_t)N_CNT * D_DIM * 4);
    float* E1      = (float*)alloc((size_t)N_CNT * D_DIM * 4);
    float* P       = (float*)alloc((size_t)2 * D_DIM * H_DIM * 4);
    float* A       = (float*)alloc((size_t)N_CNT * H_DIM * 4);
    int2*  csr     = (int2*)alloc((size_t)M_EDGE * 8);
    int*   row_ptr = (int*)alloc((size_t)(N_CNT + 1) * 4);
    int*   counts  = (int*)alloc((size_t)N_CNT * 4);
    int*   flag    = (int*)alloc(256);
    float* Wf      = (float*)alloc((size_t)WF_TOT * 4);

    k_init<<<(N_CNT + 255) / 256, 256, 0, stream>>>(uE, counts, flag);
    k_pre<<<(N_CNT * D_DIM + 255) / 256, 256, 0, stream>>>(uE, iE, E0, adj_rows, counts, flag);
    k_scan<<<1, 256, 0, stream>>>(counts, row_ptr);
    k_scatter<<<(M_EDGE / 4 + 255) / 256, 256, 0, stream>>>(adj_rows, adj_cols, adj_vals,
                                                            row_ptr, counts, csr, flag);
    // 3 propagation hops: E0 -> E1 -> E0 -> E1
    k_spmm<<<N_CNT, 256, 0, stream>>>((const float2*)E0, (float2*)E1, row_ptr, csr);
    k_spmm<<<N_CNT, 256, 0, stream>>>((const float2*)E1, (float2*)E0, row_ptr, csr);
    k_spmm<<<N_CNT, 256, 0, stream>>>((const float2*)E0, (float2*)E1, row_ptr, csr);

    k_hyperP<<<3, 256, 0, stream>>>(uHy, iHy, W1, W2, b1, g1, be1, b2, g2, be2, W3, b3,
                                    P, Wf, flag);
    k_A<<<N_CNT, H_DIM, 0, stream>>>(E1, P, Wf, A);

    HyperModel_65755949301857_kernel<<<(B_CNT + 127) / 128, 256, 0, stream>>>(
        A, userIdx, servIdx, Wf, d_out, flag);
}

// Round 9
// 469.208 us; speedup vs baseline: 1.2668x; 1.2400x over previous
//
#include <hip/hip_runtime.h>
#include <hip/hip_bf16.h>

#define U_CNT 339
#define S_CNT 5825
#define N_CNT 6164          // U + S
#define D_DIM 128
#define R_DIM 32
#define B_CNT 500000
#define M_EDGE 400000       // 2*NNZ (symmetrized)
#define H_DIM 64
#define LN_EPS 1e-5f

// fp32 weight-block offsets (elements). WF_W2 region unused since R9 (bf16 Wb replaces it)
#define WF_W2   0
#define WF_B1   4096
#define WF_G1   4160
#define WF_BE1  4224
#define WF_B2   4288
#define WF_G2   4352
#define WF_BE2  4416
#define WF_W3   4480
#define WF_B3   4544
#define WF_TOT  4545

typedef __hip_bfloat16 bf16;
typedef __attribute__((ext_vector_type(8))) short sh8;   // 8 bf16 = 4 VGPRs (MFMA A/B frag)
typedef __attribute__((ext_vector_type(4))) float f4v;   // MFMA C/D frag

__device__ __forceinline__ float b2f(bf16 x) { return __bfloat162float(x); }
__device__ __forceinline__ short f2bs(float f) {
    union { bf16 b; short s; } u;
    u.b = __float2bfloat16(f);
    return u.s;
}

// generic float-input load: isf32 selects fp32 vs bf16 interpretation
__device__ __forceinline__ float ldf(const void* p, long i, int isf32) {
    return isf32 ? ((const float*)p)[i] : b2f(((const bf16*)p)[i]);
}

// ---------- init: zero counts + dtype detect (block 0, wave 0) ----------
__global__ void k_init(const void* __restrict__ uE, int* __restrict__ counts,
                       int* __restrict__ flag) {
    int i = blockIdx.x * 256 + threadIdx.x;
    if (i < N_CNT) counts[i] = 0;
    if (blockIdx.x == 0 && threadIdx.x < 64) {
        const unsigned short* p = (const unsigned short*)uE;
        unsigned short v = p[2 * threadIdx.x];       // even bf16 element
        int e = (v >> 7) & 0xFF;                     // bf16 exponent field
        unsigned long long m = __ballot(e >= 127);   // impossible for Xavier bf16
        if (threadIdx.x == 0) flag[0] = (m != 0ull) ? 1 : 0;  // 1 => fp32 buffers
    }
}

// ---------- concat embeddings to fp32 [N,D] + edge histogram (fused) ----------
__global__ void k_pre(const void* __restrict__ uE, const void* __restrict__ iE,
                      float* __restrict__ E, const int* __restrict__ rows,
                      int* __restrict__ counts, const int* __restrict__ flag) {
    int i = blockIdx.x * 256 + threadIdx.x;
    int isf32 = flag[0];
    const int T1 = N_CNT * D_DIM;
    if (i < T1) {
        const int uTot = U_CNT * D_DIM;
        E[i] = (i < uTot) ? ldf(uE, i, isf32) : ldf(iE, i - uTot, isf32);
    }
    if (i < M_EDGE) atomicAdd(&counts[rows[i]], 1);
}

// ---------- CSR build: exclusive scan over N=6164 counts (one 256-thread block) ----------
__global__ void k_scan(const int* __restrict__ counts, int* __restrict__ row_ptr) {
    __shared__ int part[256];
    const int RPT = 25;                               // 256*25 = 6400 >= N+1
    int t = threadIdx.x;
    int base = t * RPT;
    int local[RPT];
    int s = 0;
    #pragma unroll
    for (int i = 0; i < RPT; ++i) {
        int idx = base + i;
        int v = (idx < N_CNT) ? counts[idx] : 0;
        local[i] = s;
        s += v;
    }
    part[t] = s;
    __syncthreads();
    for (int off = 1; off < 256; off <<= 1) {
        int v = (t >= off) ? part[t - off] : 0;
        __syncthreads();
        part[t] += v;
        __syncthreads();
    }
    int prefix = (t > 0) ? part[t - 1] : 0;
    #pragma unroll
    for (int i = 0; i < RPT; ++i) {
        int idx = base + i;
        if (idx <= N_CNT) row_ptr[idx] = prefix + local[i];
    }
}

// ---------- CSR build: scatter, 4 edges/thread, counts[] as down-counter ----------
__global__ void k_scatter(const int* __restrict__ rows, const int* __restrict__ cols,
                          const void* __restrict__ vals, const int* __restrict__ row_ptr,
                          int* __restrict__ counts, int2* __restrict__ csr,
                          const int* __restrict__ flag) {
    int e = (blockIdx.x * 256 + threadIdx.x) * 4;
    if (e >= M_EDGE) return;                          // M_EDGE % 4 == 0
    int isf32 = flag[0];
    int4 r4 = *(const int4*)(rows + e);
    int4 c4 = *(const int4*)(cols + e);
    float v0, v1, v2, v3;
    if (isf32) {
        float4 v = *(const float4*)((const float*)vals + e);
        v0 = v.x; v1 = v.y; v2 = v.z; v3 = v.w;
    } else {
        ushort4 v = *(const ushort4*)((const unsigned short*)vals + e);
        v0 = b2f(*(bf16*)&v.x); v1 = b2f(*(bf16*)&v.y);
        v2 = b2f(*(bf16*)&v.z); v3 = b2f(*(bf16*)&v.w);
    }
    int p0 = atomicSub(&counts[r4.x], 1) - 1;
    int p1 = atomicSub(&counts[r4.y], 1) - 1;
    int p2 = atomicSub(&counts[r4.z], 1) - 1;
    int p3 = atomicSub(&counts[r4.w], 1) - 1;
    csr[row_ptr[r4.x] + p0] = make_int2(c4.x, __float_as_int(v0));
    csr[row_ptr[r4.y] + p1] = make_int2(c4.y, __float_as_int(v1));
    csr[row_ptr[r4.z] + p2] = make_int2(c4.z, __float_as_int(v2));
    csr[row_ptr[r4.w] + p3] = make_int2(c4.w, __float_as_int(v3));
}

// ---------- SpMM: 4 waves per row split the edge list, LDS reduce ----------
__global__ void __launch_bounds__(256)
k_spmm(const float2* __restrict__ Ein2, float2* __restrict__ Eout2,
       const int* __restrict__ row_ptr, const int2* __restrict__ csr) {
    __shared__ float2 part[4][64];
    int r = blockIdx.x;
    int wave = threadIdx.x >> 6;
    int d = threadIdx.x & 63;                         // 2 dims per lane
    int k0 = row_ptr[r], k1 = row_ptr[r + 1];
    int cnt = k1 - k0;
    int chunk = (cnt + 3) >> 2;
    int ck0 = k0 + min(wave * chunk, cnt);
    int ck1 = k0 + min((wave + 1) * chunk, cnt);
    float ax0 = 0, ay0 = 0, ax1 = 0, ay1 = 0, ax2 = 0, ay2 = 0, ax3 = 0, ay3 = 0;
    int k = ck0;
    for (; k + 4 <= ck1; k += 4) {
        int2 e0 = csr[k], e1 = csr[k + 1], e2 = csr[k + 2], e3 = csr[k + 3];
        float2 f0 = Ein2[e0.x * 64 + d], f1 = Ein2[e1.x * 64 + d];
        float2 f2 = Ein2[e2.x * 64 + d], f3 = Ein2[e3.x * 64 + d];
        float v0 = __int_as_float(e0.y), v1 = __int_as_float(e1.y);
        float v2 = __int_as_float(e2.y), v3 = __int_as_float(e3.y);
        ax0 = fmaf(v0, f0.x, ax0); ay0 = fmaf(v0, f0.y, ay0);
        ax1 = fmaf(v1, f1.x, ax1); ay1 = fmaf(v1, f1.y, ay1);
        ax2 = fmaf(v2, f2.x, ax2); ay2 = fmaf(v2, f2.y, ay2);
        ax3 = fmaf(v3, f3.x, ax3); ay3 = fmaf(v3, f3.y, ay3);
    }
    for (; k < ck1; ++k) {
        int2 e = csr[k];
        float v = __int_as_float(e.y);
        float2 f = Ein2[e.x * 64 + d];
        ax0 = fmaf(v, f.x, ax0); ay0 = fmaf(v, f.y, ay0);
    }
    float2 o;
    o.x = (ax0 + ax1) + (ax2 + ax3);
    o.y = (ay0 + ay1) + (ay2 + ay3);
    part[wave][d] = o;
    __syncthreads();
    if (wave == 0) {
        float2 a = part[0][d], b = part[1][d], c = part[2][d], e = part[3][d];
        float2 s;
        s.x = (a.x + b.x) + (c.x + e.x);
        s.y = (a.y + b.y) + (c.y + e.y);
        Eout2[r * 64 + d] = s;
    }
}

// ---------- blocks 0,1: P = Hyperᵀ(Hyper @ W1part); block 2: weight prep ----------
// Block 2 packs W2 into bf16 MFMA B-fragments: Wb[((t*2+kh)*64+lane)*8+j] =
// bf16(W2[kh*32 + quad*8 + j][t*16 + (lane&15)])  (B[k][n]: k=quad*8+j, n=lane&15)
__global__ void k_hyperP(const void* __restrict__ uHy, const void* __restrict__ iHy,
                         const void* __restrict__ W1, const void* __restrict__ W2,
                         const void* __restrict__ b1, const void* __restrict__ g1,
                         const void* __restrict__ be1, const void* __restrict__ b2,
                         const void* __restrict__ g2, const void* __restrict__ be2,
                         const void* __restrict__ W3, const void* __restrict__ b3,
                         float* __restrict__ P, float* __restrict__ Wf,
                         unsigned short* __restrict__ Wb,
                         const int* __restrict__ flag) {
    int isf32 = flag[0];
    if (blockIdx.x == 2) {                            // weight prep
        for (int i = threadIdx.x; i < 4096; i += 256) {
            int j = i & 7, lane = (i >> 3) & 63, kh = (i >> 9) & 1, t = i >> 10;
            int k = kh * 32 + ((lane >> 4) & 3) * 8 + j;
            int n = t * 16 + (lane & 15);
            Wb[i] = (unsigned short)f2bs(ldf(W2, k * 64 + n, isf32));
        }
        for (int i = threadIdx.x; i < WF_TOT - 4096; i += 256) {
            int g = 4096 + i;
            float v;
            if      (g < WF_G1)  v = ldf(b1,  g - WF_B1,   isf32);
            else if (g < WF_BE1) v = ldf(g1,  g - WF_G1,   isf32);
            else if (g < WF_B2)  v = ldf(be1, g - WF_BE1,  isf32);
            else if (g < WF_G2)  v = ldf(b2,  g - WF_B2,   isf32);
            else if (g < WF_BE2) v = ldf(g2,  g - WF_G2,   isf32);
            else if (g < WF_W3)  v = ldf(be2, g - WF_BE2,  isf32);
            else if (g < WF_B3)  v = ldf(W3,  g - WF_W3,   isf32);
            else                 v = ldf(b3,  0,           isf32);
            Wf[g] = v;
        }
        return;
    }
    int side = blockIdx.x;                            // 0 = user, 1 = service
    const void* Hy = side ? iHy : uHy;                // [32][128]
    long wbase = (long)side * D_DIM * H_DIM;          // rows [side*128 .. +128) of W1
    __shared__ float Hs[R_DIM * D_DIM];               // 16 KB
    __shared__ float T[R_DIM * H_DIM];                // 8 KB
    for (int idx = threadIdx.x; idx < R_DIM * D_DIM; idx += 256)
        Hs[idx] = ldf(Hy, idx, isf32);
    __syncthreads();
    for (int idx = threadIdx.x; idx < R_DIM * H_DIM; idx += 256) {
        int a = idx >> 6, j = idx & 63;
        float acc = 0.f;
        for (int d = 0; d < D_DIM; ++d)
            acc = fmaf(Hs[a * D_DIM + d], ldf(W1, wbase + d * H_DIM + j, isf32), acc);
        T[idx] = acc;
    }
    __syncthreads();
    for (int idx = threadIdx.x; idx < D_DIM * H_DIM; idx += 256) {
        int d = idx >> 6, j = idx & 63;
        float acc = 0.f;
        #pragma unroll
        for (int a = 0; a < R_DIM; ++a)
            acc = fmaf(Hs[a * D_DIM + d], T[a * H_DIM + j], acc);
        P[side * D_DIM * H_DIM + idx] = acc;
    }
}

// ---------- A[r,:] = E[r,:] @ P(side) (+ b1 folded into user rows) ----------
__global__ void k_A(const float* __restrict__ E, const float* __restrict__ P,
                    const float* __restrict__ Wf, float* __restrict__ A) {
    int r = blockIdx.x;
    int j = threadIdx.x;                              // 64 threads
    const float* Pr = P + ((r < U_CNT) ? 0 : D_DIM * H_DIM);
    const float* Er = E + r * D_DIM;                  // wave-uniform -> scalar loads
    float acc = (r < U_CNT) ? Wf[WF_B1 + j] : 0.f;
    #pragma unroll 8
    for (int d = 0; d < D_DIM; ++d)
        acc = fmaf(Er[d], Pr[d * H_DIM + j], acc);
    A[r * H_DIM + j] = acc;
}

// ---------- fused MLP via MFMA: one wave per 16 batch rows, NO LDS ----------
// R4-R8 lesson: every VALU formulation costs >= ~4700 VALU inst/row and
// plateaus at 86-181us. mfma_f32_16x16x32_bf16 x8 does the 16x64x64 tile in
// ~40 matrix-pipe cycles. Layouts (guide-verified): A[m=lane&15][k=quad*8+j];
// B[k=quad*8+j][n=lane&15] (pre-packed bf16 Wb, coalesced 16B/lane);
// C/D col=lane&15, row=quad*4+reg. LN1 = 2 shfl_xor (row m in lanes m+16q);
// LN2/epilogue = xor-1,2,4,8 butterflies within each quad's 16 lanes.
__global__ void __launch_bounds__(256)
HyperModel_65755949301857_kernel(
      const float* __restrict__ A, const int* __restrict__ userIdx,
      const int* __restrict__ servIdx, const float* __restrict__ Wf,
      const unsigned short* __restrict__ Wb,
      void* __restrict__ out, const int* __restrict__ flag) {
    int tid = threadIdx.x;
    int wave = tid >> 6, lane = tid & 63;
    long b0 = ((long)blockIdx.x * 4 + wave) * 16;
    if (b0 >= B_CNT) return;
    int isf32 = flag[0];
    int m = lane & 15, quad = lane >> 4;

    int r = (int)b0 + m;
    int ui = userIdx[r];
    int si = servIdx[r] + U_CNT;
    const float* Aur = A + (long)ui * 64;
    const float* Asr = A + (long)si * 64;

    // gather z cols [quad*8, quad*8+8) and [32+quad*8, ...): 4 float4 per source
    float4 ul0 = *(const float4*)(Aur + quad * 8);
    float4 ul1 = *(const float4*)(Aur + quad * 8 + 4);
    float4 uh0 = *(const float4*)(Aur + 32 + quad * 8);
    float4 uh1 = *(const float4*)(Aur + 32 + quad * 8 + 4);
    float4 sl0 = *(const float4*)(Asr + quad * 8);
    float4 sl1 = *(const float4*)(Asr + quad * 8 + 4);
    float4 sh0 = *(const float4*)(Asr + 32 + quad * 8);
    float4 sh1 = *(const float4*)(Asr + 32 + quad * 8 + 4);
    float zl[8], zh[8];
    zl[0] = ul0.x + sl0.x; zl[1] = ul0.y + sl0.y; zl[2] = ul0.z + sl0.z; zl[3] = ul0.w + sl0.w;
    zl[4] = ul1.x + sl1.x; zl[5] = ul1.y + sl1.y; zl[6] = ul1.z + sl1.z; zl[7] = ul1.w + sl1.w;
    zh[0] = uh0.x + sh0.x; zh[1] = uh0.y + sh0.y; zh[2] = uh0.z + sh0.z; zh[3] = uh0.w + sh0.w;
    zh[4] = uh1.x + sh1.x; zh[5] = uh1.y + sh1.y; zh[6] = uh1.z + sh1.z; zh[7] = uh1.w + sh1.w;

    // LN1: row m spans lanes {m, m+16, m+32, m+48}
    float s = 0.f, q = 0.f;
    #pragma unroll
    for (int j = 0; j < 8; ++j) {
        s += zl[j] + zh[j];
        q = fmaf(zl[j], zl[j], q);
        q = fmaf(zh[j], zh[j], q);
    }
    s += __shfl_xor(s, 16, 64); s += __shfl_xor(s, 32, 64);
    q += __shfl_xor(q, 16, 64); q += __shfl_xor(q, 32, 64);
    float mu = s * (1.f / 64.f);
    float rs = rsqrtf(q * (1.f / 64.f) - mu * mu + LN_EPS);
    float nm = -mu * rs;

    // h = relu(LN1 * g1 + be1) -> bf16 A-fragments (k = quad*8+j and 32+quad*8+j)
    const float* G1l = Wf + WF_G1 + quad * 8;
    const float* BE1l = Wf + WF_BE1 + quad * 8;
    sh8 a0, a1;
    #pragma unroll
    for (int j = 0; j < 8; ++j) {
        float h0 = fmaxf(fmaf(fmaf(zl[j], rs, nm), G1l[j],      BE1l[j]),      0.f);
        float h1 = fmaxf(fmaf(fmaf(zh[j], rs, nm), G1l[32 + j], BE1l[32 + j]), 0.f);
        a0[j] = f2bs(h0);
        a1[j] = f2bs(h1);
    }

    // 8 MFMAs: 4 col-tiles x 2 K-halves
    const sh8* Bp = (const sh8*)Wb;
    sh8 b00 = Bp[0 * 64 + lane], b01 = Bp[1 * 64 + lane];
    sh8 b10 = Bp[2 * 64 + lane], b11 = Bp[3 * 64 + lane];
    sh8 b20 = Bp[4 * 64 + lane], b21 = Bp[5 * 64 + lane];
    sh8 b30 = Bp[6 * 64 + lane], b31 = Bp[7 * 64 + lane];
    f4v acc0 = {0.f, 0.f, 0.f, 0.f}, acc1 = acc0, acc2 = acc0, acc3 = acc0;
    acc0 = __builtin_amdgcn_mfma_f32_16x16x32_bf16(a0, b00, acc0, 0, 0, 0);
    acc0 = __builtin_amdgcn_mfma_f32_16x16x32_bf16(a1, b01, acc0, 0, 0, 0);
    acc1 = __builtin_amdgcn_mfma_f32_16x16x32_bf16(a0, b10, acc1, 0, 0, 0);
    acc1 = __builtin_amdgcn_mfma_f32_16x16x32_bf16(a1, b11, acc1, 0, 0, 0);
    acc2 = __builtin_amdgcn_mfma_f32_16x16x32_bf16(a0, b20, acc2, 0, 0, 0);
    acc2 = __builtin_amdgcn_mfma_f32_16x16x32_bf16(a1, b21, acc2, 0, 0, 0);
    acc3 = __builtin_amdgcn_mfma_f32_16x16x32_bf16(a0, b30, acc3, 0, 0, 0);
    acc3 = __builtin_amdgcn_mfma_f32_16x16x32_bf16(a1, b31, acc3, 0, 0, 0);

    // y[t][reg] = acc_t[reg] + b2[t*16+m]; lane holds rows quad*4+reg, col t*16+m
    float b2c0 = Wf[WF_B2 + 0 * 16 + m], b2c1 = Wf[WF_B2 + 1 * 16 + m];
    float b2c2 = Wf[WF_B2 + 2 * 16 + m], b2c3 = Wf[WF_B2 + 3 * 16 + m];
    float y0[4], y1[4], y2[4], y3[4];
    float srow[4], qrow[4];
    #pragma unroll
    for (int reg = 0; reg < 4; ++reg) {
        y0[reg] = acc0[reg] + b2c0;
        y1[reg] = acc1[reg] + b2c1;
        y2[reg] = acc2[reg] + b2c2;
        y3[reg] = acc3[reg] + b2c3;
        srow[reg] = (y0[reg] + y1[reg]) + (y2[reg] + y3[reg]);
        float qa = y0[reg] * y0[reg];
        qa = fmaf(y1[reg], y1[reg], qa);
        qa = fmaf(y2[reg], y2[reg], qa);
        qa = fmaf(y3[reg], y3[reg], qa);
        qrow[reg] = qa;
    }
    #pragma unroll
    for (int off = 1; off < 16; off <<= 1) {
        #pragma unroll
        for (int reg = 0; reg < 4; ++reg) {
            srow[reg] += __shfl_xor(srow[reg], off, 64);
            qrow[reg] += __shfl_xor(qrow[reg], off, 64);
        }
    }

    // epilogue: LN2 + relu*g2+be2 + W3 dot
    float g2c0 = Wf[WF_G2 + m],      g2c1 = Wf[WF_G2 + 16 + m];
    float g2c2 = Wf[WF_G2 + 32 + m], g2c3 = Wf[WF_G2 + 48 + m];
    float e2c0 = Wf[WF_BE2 + m],      e2c1 = Wf[WF_BE2 + 16 + m];
    float e2c2 = Wf[WF_BE2 + 32 + m], e2c3 = Wf[WF_BE2 + 48 + m];
    float w3c0 = Wf[WF_W3 + m],      w3c1 = Wf[WF_W3 + 16 + m];
    float w3c2 = Wf[WF_W3 + 32 + m], w3c3 = Wf[WF_W3 + 48 + m];
    float b3v = Wf[WF_B3];
    float o[4];
    #pragma unroll
    for (int reg = 0; reg < 4; ++reg) {
        float mu2 = srow[reg] * (1.f / 64.f);
        float rs2 = rsqrtf(qrow[reg] * (1.f / 64.f) - mu2 * mu2 + LN_EPS);
        float nm2 = -mu2 * rs2;
        float t0 = fmaxf(fmaf(fmaf(y0[reg], rs2, nm2), g2c0, e2c0), 0.f);
        float t1 = fmaxf(fmaf(fmaf(y1[reg], rs2, nm2), g2c1, e2c1), 0.f);
        float t2 = fmaxf(fmaf(fmaf(y2[reg], rs2, nm2), g2c2, e2c2), 0.f);
        float t3 = fmaxf(fmaf(fmaf(y3[reg], rs2, nm2), g2c3, e2c3), 0.f);
        o[reg] = fmaf(t0, w3c0, fmaf(t1, w3c1, fmaf(t2, w3c2, t3 * w3c3)));
    }
    #pragma unroll
    for (int off = 1; off < 16; off <<= 1) {
        #pragma unroll
        for (int reg = 0; reg < 4; ++reg) o[reg] += __shfl_xor(o[reg], off, 64);
    }
    if (m == 0) {                                     // 4 rows b0+quad*4..+3
        long rb = b0 + quad * 4;
        if (isf32) {
            float4 v = make_float4(o[0] + b3v, o[1] + b3v, o[2] + b3v, o[3] + b3v);
            *(float4*)((float*)out + rb) = v;
        } else {
            ushort4 v;
            v.x = (unsigned short)f2bs(o[0] + b3v);
            v.y = (unsigned short)f2bs(o[1] + b3v);
            v.z = (unsigned short)f2bs(o[2] + b3v);
            v.w = (unsigned short)f2bs(o[3] + b3v);
            *(ushort4*)((bf16*)out + rb) = v;
        }
    }
}

extern "C" __attribute__((visibility("default")))
void kernel_launch(void* const* d_in, const int* in_sizes, int n_in,
                   void* d_out, int out_size, void* d_ws, size_t ws_size,
                   hipStream_t stream) {
    const void* uE   = d_in[0];
    const void* iE   = d_in[1];
    const void* uHy  = d_in[2];
    const void* iHy  = d_in[3];
    const void* W1   = d_in[4];
    const void* b1   = d_in[5];
    const void* g1   = d_in[6];
    const void* be1  = d_in[7];
    const void* W2   = d_in[8];
    const void* b2   = d_in[9];
    const void* g2   = d_in[10];
    const void* be2  = d_in[11];
    const void* W3   = d_in[12];
    const void* b3   = d_in[13];
    const void* adj_vals = d_in[14];
    const int*  adj_rows = (const int*)d_in[15];
    const int*  adj_cols = (const int*)d_in[16];
    const int*  userIdx  = (const int*)d_in[17];
    const int*  servIdx  = (const int*)d_in[18];

    char* w = (char*)d_ws;
    size_t off = 0;
    auto alloc = [&](size_t bytes) -> char* {
        char* p = w + off;
        off += (bytes + 255) & ~(size_t)255;
        return p;
    };
    float* E0      = (float*)alloc((size_t)N_CNT * D_DIM * 4);
    float* E1      = (float*)alloc((size_t)N_CNT * D_DIM * 4);
    float* P       = (float*)alloc((size_t)2 * D_DIM * H_DIM * 4);
    float* A       = (float*)alloc((size_t)N_CNT * H_DIM * 4);
    int2*  csr     = (int2*)alloc((size_t)M_EDGE * 8);
    int*   row_ptr = (int*)alloc((size_t)(N_CNT + 1) * 4);
    int*   counts  = (int*)alloc((size_t)N_CNT * 4);
    int*   flag    = (int*)alloc(256);
    float* Wf      = (float*)alloc((size_t)WF_TOT * 4);
    unsigned short* Wb = (unsigned short*)alloc((size_t)4096 * 2);

    k_init<<<(N_CNT + 255) / 256, 256, 0, stream>>>(uE, counts, flag);
    k_pre<<<(N_CNT * D_DIM + 255) / 256, 256, 0, stream>>>(uE, iE, E0, adj_rows, counts, flag);
    k_scan<<<1, 256, 0, stream>>>(counts, row_ptr);
    k_scatter<<<(M_EDGE / 4 + 255) / 256, 256, 0, stream>>>(adj_rows, adj_cols, adj_vals,
                                                            row_ptr, counts, csr, flag);
    // 3 propagation hops: E0 -> E1 -> E0 -> E1
    k_spmm<<<N_CNT, 256, 0, stream>>>((const float2*)E0, (float2*)E1, row_ptr, csr);
    k_spmm<<<N_CNT, 256, 0, stream>>>((const float2*)E1, (float2*)E0, row_ptr, csr);
    k_spmm<<<N_CNT, 256, 0, stream>>>((const float2*)E0, (float2*)E1, row_ptr, csr);

    k_hyperP<<<3, 256, 0, stream>>>(uHy, iHy, W1, W2, b1, g1, be1, b2, g2, be2, W3, b3,
                                    P, Wf, Wb, flag);
    k_A<<<N_CNT, H_DIM, 0, stream>>>(E1, P, Wf, A);

    int nwaves = B_CNT / 16;                          // 31250
    HyperModel_65755949301857_kernel<<<(nwaves + 3) / 4, 256, 0, stream>>>(
        A, userIdx, servIdx, Wf, Wb, d_out, flag);
}